// Round 13
// baseline (164.233 us; speedup 1.0000x reference)
//
#include <hip/hip_runtime.h>

// CASREL loss, B=32,S=512,H=1024,R=64 -> scalar fp32 loss.
// v14 = v8 (best verified, 161.4us) + ONE surgical change: the two per-chunk
// __syncthreads (which compile to s_waitcnt vmcnt(0) lgkmcnt(0); s_barrier,
// draining the just-issued prefetch loads every round - the root cause of
// the 42us plateau, v1-v8) are replaced by {s_waitcnt lgkmcnt(0) + raw
// s_barrier}. LDS-only waits are sufficient: barrier (a) orders ds_reads of
// the old chunk vs overwrite; barrier (b) orders ds_writes vs compute reads.
// Global loads (vmcnt) issued in iter t now stay in flight across barrier(b)
// and COMPUTE(t), draining at their register use in WRITE_LDS of iter t+1 -
// a full compute phase later. No math/layout change: bit-identical to v8.

#define B_  32
#define S_  512
#define H_  1024
#define R_  64
#define M_  (B_ * S_)      // 16384 rows
#define NPAD 160           // 130 valid cols padded
#define NVALID 130
#define BK 128
#define BKP 136            // A LDS pad (shorts)
#define MT 64              // rows per block
#define NCHUNK (H_ / BK)   // 8
#define TBLK 20            // transpose blocks (5 n-tiles x 4 k-tiles)
#define NTHR 512           // 8 waves

typedef __attribute__((ext_vector_type(4))) float  floatx4;
typedef __attribute__((ext_vector_type(8))) short  short8;     // 8 bf16
typedef __attribute__((ext_vector_type(4))) unsigned short u16x4;
typedef __attribute__((ext_vector_type(8))) unsigned short u16x8;

__device__ __forceinline__ unsigned short f2bf(float f) {
    unsigned int u = __float_as_uint(f);
    u = (u + 0x7FFFu + ((u >> 16) & 1u)) >> 16;   // RNE
    return (unsigned short)u;
}

__device__ __forceinline__ u16x8 cvt8u(float4 a, float4 b) {
    u16x8 u;
    u[0] = f2bf(a.x); u[1] = f2bf(a.y); u[2] = f2bf(a.z); u[3] = f2bf(a.w);
    u[4] = f2bf(b.x); u[5] = f2bf(b.y); u[6] = f2bf(b.z); u[7] = f2bf(b.w);
    return u;
}

// ---- K1 (merged): blocks [0,TBLK) transpose WtG; blocks [TBLK,TBLK+B_) subj ----
__global__ __launch_bounds__(256) void aux_kernel(
        const float* __restrict__ ctx, const float* __restrict__ head,
        const float* __restrict__ tail, const float* __restrict__ masks,
        const float* __restrict__ Wo_h, const float* __restrict__ Wo_t,
        const float* __restrict__ Ws_h, const float* __restrict__ Ws_t,
        const float* __restrict__ bo_h, const float* __restrict__ bo_t,
        const float* __restrict__ bs_h, const float* __restrict__ bs_t,
        unsigned short* __restrict__ WtG, float* __restrict__ rowBias,
        float* __restrict__ accum) {
    const int tid = threadIdx.x;
    __shared__ float tr[32][257];      // transpose tile (pad 257: conflict-free)
    __shared__ float subj[H_];
    __shared__ float partS[4][256];
    __shared__ int cnt;
    __shared__ int   sidx[8];
    __shared__ float sw[8];

    if (blockIdx.x < TBLK) {
        const int kt = blockIdx.x / 5, nt = blockIdx.x % 5;
        const int k0 = kt * 256, n0 = nt * 32;
        if (n0 < 128) {
            const float* src = (n0 < 64) ? Wo_h : Wo_t;
            const int cb = n0 & 63;
            const int nn = tid & 31, kk = tid >> 5;   // 8 k-rows per pass
#pragma unroll
            for (int i = 0; i < 32; ++i) {
                const int k = k0 + i * 8 + kk;
                tr[nn][i * 8 + kk] = src[(size_t)k * R_ + cb + nn];
            }
            __syncthreads();
#pragma unroll
            for (int p = 0; p < 4; ++p) {
                const int chunk = p * 256 + tid;
                const int n = chunk >> 5;             // 0..31
                const int kc = (chunk & 31) * 8;
                u16x8 v;
#pragma unroll
                for (int j = 0; j < 8; ++j) v[j] = f2bf(tr[n][kc + j]);
                *(u16x8*)(WtG + (size_t)(n0 + n) * H_ + k0 + kc) = v;
            }
        } else {
#pragma unroll
            for (int p = 0; p < 4; ++p) {
                const int chunk = p * 256 + tid;
                const int n = 128 + (chunk >> 5);
                const int kc = (chunk & 31) * 8;
                u16x8 v;
#pragma unroll
                for (int j = 0; j < 8; ++j) {
                    float f = (n == 128) ? Ws_h[k0 + kc + j]
                            : (n == 129) ? Ws_t[k0 + kc + j] : 0.0f;
                    v[j] = f2bf(f);
                }
                *(u16x8*)(WtG + (size_t)n * H_ + k0 + kc) = v;
            }
        }
        return;
    }

    const int b = blockIdx.x - TBLK;
    if (tid == 0) cnt = 0;
    __syncthreads();
    float msk = 0.0f;
    for (int s = tid; s < S_; s += 256) {
        float w = 0.5f * (head[b * S_ + s] + tail[b * S_ + s]);
        if (w != 0.0f) {
            int i = atomicAdd(&cnt, 1);
            if (i < 8) { sidx[i] = s; sw[i] = w; }
        }
        msk += masks[b * S_ + s];
    }
    for (int o = 32; o > 0; o >>= 1) msk += __shfl_down(msk, o, 64);
    if ((tid & 63) == 0) atomicAdd(&accum[1], msk);
    __syncthreads();
    const int nnz = cnt < 8 ? cnt : 8;
    for (int h = tid; h < H_; h += 256) {
        float a = 0.0f;
        for (int i = 0; i < nnz; i++)
            a += sw[i] * ctx[((size_t)b * S_ + sidx[i]) * H_ + h];
        subj[h] = a;
    }
    __syncthreads();
    {   // rowBias dot: thread = (c-group of 4, k-slice of 128); float4 W loads
        const int cg = tid & 31;
        const int ks = tid >> 5;
        const int c4 = cg * 4;
        const float* W = (c4 < 64) ? Wo_h : Wo_t;
        const int cc = c4 & 63;
        const int kk0 = ks * 128;
        float ax = 0.f, ay = 0.f, az = 0.f, aw2 = 0.f;
#pragma unroll 4
        for (int k = kk0; k < kk0 + 128; ++k) {
            const float4 w = *(const float4*)(W + (size_t)k * R_ + cc);
            const float sv = subj[k];
            ax += sv * w.x; ay += sv * w.y; az += sv * w.z; aw2 += sv * w.w;
        }
        partS[0][tid] = ax; partS[1][tid] = ay;
        partS[2][tid] = az; partS[3][tid] = aw2;
    }
    __syncthreads();
    if (tid < NPAD) {
        float bias = tid < 64  ? bo_h[tid]
                   : tid < 128 ? bo_t[tid - 64]
                   : tid == 128 ? bs_h[0]
                   : tid == 129 ? bs_t[0] : 0.0f;
        float a2 = 0.0f;
        if (tid < 128) {
            const int g = tid >> 2, j = tid & 3;
#pragma unroll
            for (int s = 0; s < 8; ++s) a2 += partS[j][s * 32 + g];
        }
        rowBias[b * NPAD + tid] = bias + a2;
    }
}

// ---- K2: MT=64, 8-wave, BK=128 GEMM, lgkm-only barriers + BCE + finalize ----
__global__ __launch_bounds__(NTHR, 2) void main_kernel(
        const float* __restrict__ ctx, const unsigned short* __restrict__ WtG,
        const float* __restrict__ rowBias, const float* __restrict__ masks,
        const float* __restrict__ ash, const float* __restrict__ ast,
        const float* __restrict__ oh, const float* __restrict__ ot,
        float* __restrict__ accum, float* __restrict__ out) {
    __shared__ __align__(16) unsigned short Asm[MT * BKP];   // 17.4 KB
    __shared__ __align__(16) unsigned short Bsm[NPAD * BK];  // 40 KB
    __shared__ float rbuf[8];

    const int tid  = threadIdx.x;
    const int gm0  = blockIdx.x * MT;
    const int b    = gm0 >> 9;                // 512 rows per batch (MT=64 divides)
    const int wave = tid >> 6, lane = tid & 63;
    const int wm = wave & 3;            // row group (16 rows), 0..3
    const int wn = wave >> 2;           // col half (80 cols = 5 tiles), 0..1
    const int lr = lane & 15, q = lane >> 4;   // q in 0..3

    // A staging: thread -> row ar = tid>>3 (0..63), 16 floats at col (tid&7)*16
    const int ar = tid >> 3, as_ = (tid & 7) * 16;
    const float* aSrc = ctx + (size_t)(gm0 + ar) * H_ + as_;
    unsigned short* aDst = &Asm[ar * BKP + as_];

    // B staging: rows {br, br+64, br+128(if tid<256)}, 16 shorts at (tid&7)*16
    // LDS layout: [row][128] shorts, byte col XOR-swizzled by ((row&7)<<4)
    const int br = tid >> 3, bs0 = (tid & 7) * 16;   // shorts
    const unsigned short* bSrc = WtG + (size_t)br * H_ + bs0;
    const int bswz = (br & 7) << 4;                  // rows differ by 64 -> same swz
    char* bDstB = (char*)Bsm + br * 256;             // + ((bytecol)^bswz)
    const bool bp2 = (tid < 256);                    // wave-uniform (waves 0-3)

    // compute-side fragment offsets
    const int aOff = (wm * 16 + lr) * BKP + q * 8;   // shorts
    int bOff[5];
#pragma unroll
    for (int tt = 0; tt < 5; ++tt) {
        const int row = wn * 80 + tt * 16 + lr;
        bOff[tt] = row * 256 + ((q * 16) ^ ((row & 7) << 4));   // bytes; ^(kk<<1) per substep
    }

    floatx4 acc[5];
#pragma unroll
    for (int tt = 0; tt < 5; ++tt) acc[tt] = (floatx4){0.f, 0.f, 0.f, 0.f};

    // staging registers for one chunk
    float4 aR[4];
    u16x8  bR[6];

#define LOADREGS(k0) do {                                                      \
        _Pragma("unroll")                                                      \
        for (int i = 0; i < 4; ++i)                                            \
            aR[i] = *(const float4*)(aSrc + (k0) + i * 4);                     \
        bR[0] = *(const u16x8*)(bSrc + (k0));                                  \
        bR[1] = *(const u16x8*)(bSrc + (k0) + 8);                              \
        bR[2] = *(const u16x8*)(bSrc + (size_t)64 * H_ + (k0));                \
        bR[3] = *(const u16x8*)(bSrc + (size_t)64 * H_ + (k0) + 8);            \
        if (bp2) {                                                             \
            bR[4] = *(const u16x8*)(bSrc + (size_t)128 * H_ + (k0));           \
            bR[5] = *(const u16x8*)(bSrc + (size_t)128 * H_ + (k0) + 8);       \
        }                                                                      \
    } while (0)

#define WRITE_LDS() do {                                                       \
        *(u16x8*)(aDst)     = cvt8u(aR[0], aR[1]);                             \
        *(u16x8*)(aDst + 8) = cvt8u(aR[2], aR[3]);                             \
        *(u16x8*)(bDstB + ((bs0 * 2)      ^ bswz)) = bR[0];                    \
        *(u16x8*)(bDstB + ((bs0 * 2 + 16) ^ bswz)) = bR[1];                    \
        *(u16x8*)(bDstB + 64 * 256 + ((bs0 * 2)      ^ bswz)) = bR[2];         \
        *(u16x8*)(bDstB + 64 * 256 + ((bs0 * 2 + 16) ^ bswz)) = bR[3];         \
        if (bp2) {                                                             \
            *(u16x8*)(bDstB + 128 * 256 + ((bs0 * 2)      ^ bswz)) = bR[4];    \
            *(u16x8*)(bDstB + 128 * 256 + ((bs0 * 2 + 16) ^ bswz)) = bR[5];    \
        }                                                                      \
    } while (0)

    LOADREGS(0);
    for (int t = 0; t < NCHUNK; ++t) {
        // (a) all waves done READING the previous chunk. LDS-only wait:
        // global prefetch loads (vmcnt) stay in flight across this barrier.
        asm volatile("s_waitcnt lgkmcnt(0)" ::: "memory");
        __builtin_amdgcn_s_barrier();
        WRITE_LDS();                     // compiler waits vmcnt here (reg uses)
        if (t < NCHUNK - 1) LOADREGS((t + 1) * BK);   // issue next-chunk loads
        // (b) all waves' LDS writes visible. LDS-only wait: the loads just
        // issued remain outstanding through COMPUTE below.
        asm volatile("s_waitcnt lgkmcnt(0)" ::: "memory");
        __builtin_amdgcn_s_barrier();
        // compute chunk t; chunk t+1 loads fly under this whole phase
#pragma unroll
        for (int kk = 0; kk < BK; kk += 32) {
            short8 afr = *(const short8*)&Asm[aOff + kk];
#pragma unroll
            for (int tt = 0; tt < 5; ++tt) {
                short8 bfr = *(const short8*)((const char*)Bsm + (bOff[tt] ^ (kk << 1)));
                acc[tt] = __builtin_amdgcn_mfma_f32_16x16x32_bf16(afr, bfr, acc[tt], 0, 0, 0);
            }
        }
    }
#undef LOADREGS
#undef WRITE_LDS

    // epilogue: logits -> BCE * mask -> sum
    float lsum = 0.0f;
#pragma unroll
    for (int tt = 0; tt < 5; ++tt) {
        const int col = wn * 80 + tt * 16 + lr;
        if (col < NVALID) {
            const float rb = rowBias[b * NPAD + col];
#pragma unroll
            for (int i = 0; i < 4; ++i) {
                const int row = gm0 + wm * 16 + q * 4 + i;
                const float l = acc[tt][i] + rb;
                float tgt;
                if (col < 64)        tgt = oh[(size_t)row * R_ + col];
                else if (col < 128)  tgt = ot[(size_t)row * R_ + (col - 64)];
                else if (col == 128) tgt = ash[row];
                else                 tgt = ast[row];
                const float mk = masks[row];
                const float bce = fmaxf(l, 0.0f) - l * tgt + log1pf(__expf(-fabsf(l)));
                lsum += bce * mk;
            }
        }
    }
    for (int o = 32; o > 0; o >>= 1) lsum += __shfl_down(lsum, o, 64);
    if (lane == 0) rbuf[wave] = lsum;
    __syncthreads();
    if (tid == 0) {
        float s0 = 0.0f;
#pragma unroll
        for (int w = 0; w < 8; ++w) s0 += rbuf[w];
        atomicAdd(&accum[0], s0);
        __threadfence();
        const unsigned int prev = atomicAdd((unsigned int*)(accum + 2), 1u);
        if (prev == gridDim.x - 1) {   // last block finalizes
            const float s = atomicAdd(&accum[0], 0.0f);
            const float m = atomicAdd(&accum[1], 0.0f);
            out[0] = s / m;
        }
    }
}

extern "C" void kernel_launch(void* const* d_in, const int* in_sizes, int n_in,
                              void* d_out, int out_size, void* d_ws, size_t ws_size,
                              hipStream_t stream) {
    const float* ctx   = (const float*)d_in[0];
    const float* masks = (const float*)d_in[1];
    const float* ash   = (const float*)d_in[2];
    const float* ast   = (const float*)d_in[3];
    const float* sh    = (const float*)d_in[4];
    const float* st    = (const float*)d_in[5];
    const float* oh    = (const float*)d_in[6];
    const float* ot    = (const float*)d_in[7];
    const float* Ws_h  = (const float*)d_in[8];
    const float* bs_h  = (const float*)d_in[9];
    const float* Ws_t  = (const float*)d_in[10];
    const float* bs_t  = (const float*)d_in[11];
    const float* Wo_h  = (const float*)d_in[12];
    const float* bo_h  = (const float*)d_in[13];
    const float* Wo_t  = (const float*)d_in[14];
    const float* bo_t  = (const float*)d_in[15];
    float* out = (float*)d_out;

    char* ws = (char*)d_ws;
    float* accum   = (float*)(ws + 0);                 // [0]=loss, [1]=msum, [2]=counter
    float* rowBias = (float*)(ws + 256);               // [32][160] fp32
    unsigned short* WtG = (unsigned short*)(ws + 256 + 32 * NPAD * 4); // [160][1024] bf16

    hipMemsetAsync(accum, 0, 12, stream);
    aux_kernel<<<TBLK + B_, 256, 0, stream>>>(ctx, sh, st, masks, Wo_h, Wo_t,
                                              Ws_h, Ws_t, bo_h, bo_t, bs_h, bs_t,
                                              WtG, rowBias, accum);
    main_kernel<<<M_ / MT, NTHR, 0, stream>>>(ctx, WtG, rowBias, masks,
                                              ash, ast, oh, ot, accum, out);
}

// Round 14
// 161.235 us; speedup vs baseline: 1.0186x; 1.0186x over previous
//
#include <hip/hip_runtime.h>

// CASREL loss, B=32,S=512,H=1024,R=64 -> scalar fp32 loss.
// v15 = v8 + B-fragment reuse. Counter-derived model: LDS pipe is the
// busiest resource (~45% of round: 16 waves x 24 ds_read_b128 + writes +
// 2.5M conflict cy), and B frags are read x4 (once per row-group wave).
// Restructure: 4 waves (wm=32-row group x wn=col-half), each computes TWO
// row-tiles per B read: {2 A reads, 5 B reads, 10 MFMA}/substep. Block LDS
// reads/round 192->112. Staging reuses v8's exact 512-thread maps, executed
// twice per 256-thread block (vtid = tid, tid+256): same coalescing/swizzle/
// layout/K-order -> bit-identical numerics. Occupancy halves (v5: irrelevant).

#define B_  32
#define S_  512
#define H_  1024
#define R_  64
#define M_  (B_ * S_)      // 16384 rows
#define NPAD 160           // 130 valid cols padded
#define NVALID 130
#define BK 128
#define BKP 136            // A LDS pad (shorts)
#define MT 64              // rows per block
#define NCHUNK (H_ / BK)   // 8
#define TBLK 20            // transpose blocks (5 n-tiles x 4 k-tiles)
#define NTHR 256           // 4 waves

typedef __attribute__((ext_vector_type(4))) float  floatx4;
typedef __attribute__((ext_vector_type(8))) short  short8;     // 8 bf16
typedef __attribute__((ext_vector_type(4))) unsigned short u16x4;
typedef __attribute__((ext_vector_type(8))) unsigned short u16x8;

__device__ __forceinline__ unsigned short f2bf(float f) {
    unsigned int u = __float_as_uint(f);
    u = (u + 0x7FFFu + ((u >> 16) & 1u)) >> 16;   // RNE
    return (unsigned short)u;
}

__device__ __forceinline__ u16x8 cvt8u(float4 a, float4 b) {
    u16x8 u;
    u[0] = f2bf(a.x); u[1] = f2bf(a.y); u[2] = f2bf(a.z); u[3] = f2bf(a.w);
    u[4] = f2bf(b.x); u[5] = f2bf(b.y); u[6] = f2bf(b.z); u[7] = f2bf(b.w);
    return u;
}

// ---- K1 (merged): blocks [0,TBLK) transpose WtG; blocks [TBLK,TBLK+B_) subj ----
__global__ __launch_bounds__(256) void aux_kernel(
        const float* __restrict__ ctx, const float* __restrict__ head,
        const float* __restrict__ tail, const float* __restrict__ masks,
        const float* __restrict__ Wo_h, const float* __restrict__ Wo_t,
        const float* __restrict__ Ws_h, const float* __restrict__ Ws_t,
        const float* __restrict__ bo_h, const float* __restrict__ bo_t,
        const float* __restrict__ bs_h, const float* __restrict__ bs_t,
        unsigned short* __restrict__ WtG, float* __restrict__ rowBias,
        float* __restrict__ accum) {
    const int tid = threadIdx.x;
    __shared__ float tr[32][257];      // transpose tile (pad 257: conflict-free)
    __shared__ float subj[H_];
    __shared__ float partS[4][256];
    __shared__ int cnt;
    __shared__ int   sidx[8];
    __shared__ float sw[8];

    if (blockIdx.x < TBLK) {
        const int kt = blockIdx.x / 5, nt = blockIdx.x % 5;
        const int k0 = kt * 256, n0 = nt * 32;
        if (n0 < 128) {
            const float* src = (n0 < 64) ? Wo_h : Wo_t;
            const int cb = n0 & 63;
            const int nn = tid & 31, kk = tid >> 5;   // 8 k-rows per pass
#pragma unroll
            for (int i = 0; i < 32; ++i) {
                const int k = k0 + i * 8 + kk;
                tr[nn][i * 8 + kk] = src[(size_t)k * R_ + cb + nn];
            }
            __syncthreads();
#pragma unroll
            for (int p = 0; p < 4; ++p) {
                const int chunk = p * 256 + tid;
                const int n = chunk >> 5;             // 0..31
                const int kc = (chunk & 31) * 8;
                u16x8 v;
#pragma unroll
                for (int j = 0; j < 8; ++j) v[j] = f2bf(tr[n][kc + j]);
                *(u16x8*)(WtG + (size_t)(n0 + n) * H_ + k0 + kc) = v;
            }
        } else {
#pragma unroll
            for (int p = 0; p < 4; ++p) {
                const int chunk = p * 256 + tid;
                const int n = 128 + (chunk >> 5);
                const int kc = (chunk & 31) * 8;
                u16x8 v;
#pragma unroll
                for (int j = 0; j < 8; ++j) {
                    float f = (n == 128) ? Ws_h[k0 + kc + j]
                            : (n == 129) ? Ws_t[k0 + kc + j] : 0.0f;
                    v[j] = f2bf(f);
                }
                *(u16x8*)(WtG + (size_t)n * H_ + k0 + kc) = v;
            }
        }
        return;
    }

    const int b = blockIdx.x - TBLK;
    if (tid == 0) cnt = 0;
    __syncthreads();
    float msk = 0.0f;
    for (int s = tid; s < S_; s += 256) {
        float w = 0.5f * (head[b * S_ + s] + tail[b * S_ + s]);
        if (w != 0.0f) {
            int i = atomicAdd(&cnt, 1);
            if (i < 8) { sidx[i] = s; sw[i] = w; }
        }
        msk += masks[b * S_ + s];
    }
    for (int o = 32; o > 0; o >>= 1) msk += __shfl_down(msk, o, 64);
    if ((tid & 63) == 0) atomicAdd(&accum[1], msk);
    __syncthreads();
    const int nnz = cnt < 8 ? cnt : 8;
    for (int h = tid; h < H_; h += 256) {
        float a = 0.0f;
        for (int i = 0; i < nnz; i++)
            a += sw[i] * ctx[((size_t)b * S_ + sidx[i]) * H_ + h];
        subj[h] = a;
    }
    __syncthreads();
    {   // rowBias dot: thread = (c-group of 4, k-slice of 128); float4 W loads
        const int cg = tid & 31;
        const int ks = tid >> 5;
        const int c4 = cg * 4;
        const float* W = (c4 < 64) ? Wo_h : Wo_t;
        const int cc = c4 & 63;
        const int kk0 = ks * 128;
        float ax = 0.f, ay = 0.f, az = 0.f, aw2 = 0.f;
#pragma unroll 4
        for (int k = kk0; k < kk0 + 128; ++k) {
            const float4 w = *(const float4*)(W + (size_t)k * R_ + cc);
            const float sv = subj[k];
            ax += sv * w.x; ay += sv * w.y; az += sv * w.z; aw2 += sv * w.w;
        }
        partS[0][tid] = ax; partS[1][tid] = ay;
        partS[2][tid] = az; partS[3][tid] = aw2;
    }
    __syncthreads();
    if (tid < NPAD) {
        float bias = tid < 64  ? bo_h[tid]
                   : tid < 128 ? bo_t[tid - 64]
                   : tid == 128 ? bs_h[0]
                   : tid == 129 ? bs_t[0] : 0.0f;
        float a2 = 0.0f;
        if (tid < 128) {
            const int g = tid >> 2, j = tid & 3;
#pragma unroll
            for (int s = 0; s < 8; ++s) a2 += partS[j][s * 32 + g];
        }
        rowBias[b * NPAD + tid] = bias + a2;
    }
}

// ---- K2: MT=64, 4-wave (B-frag reuse x2), BK=128 GEMM + BCE + finalize ----
__global__ __launch_bounds__(NTHR, 2) void main_kernel(
        const float* __restrict__ ctx, const unsigned short* __restrict__ WtG,
        const float* __restrict__ rowBias, const float* __restrict__ masks,
        const float* __restrict__ ash, const float* __restrict__ ast,
        const float* __restrict__ oh, const float* __restrict__ ot,
        float* __restrict__ accum, float* __restrict__ out) {
    __shared__ __align__(16) unsigned short Asm[MT * BKP];   // 17.4 KB
    __shared__ __align__(16) unsigned short Bsm[NPAD * BK];  // 40 KB
    __shared__ float rbuf[4];

    const int tid  = threadIdx.x;
    const int gm0  = blockIdx.x * MT;
    const int b    = gm0 >> 9;
    const int wave = tid >> 6, lane = tid & 63;
    const int wm = wave & 1;            // 32-row group, 0..1
    const int wn = wave >> 1;           // col half (80 cols = 5 tiles), 0..1
    const int lr = lane & 15, q = lane >> 4;   // q in 0..3

    // ---- staging: v8's 512-thread maps run twice (vtid = tid, tid+256) ----
    // A: row ar = vt>>3 (0..63), 16 floats at col (vt&7)*16
    const int ar0 = tid >> 3,        as0 = (tid & 7) * 16;
    const int ar1 = (tid + 256) >> 3;                        // 32..63, same as0
    const float* aSrc0 = ctx + (size_t)(gm0 + ar0) * H_ + as0;
    const float* aSrc1 = ctx + (size_t)(gm0 + ar1) * H_ + as0;
    unsigned short* aDst0 = &Asm[ar0 * BKP + as0];
    unsigned short* aDst1 = &Asm[ar1 * BKP + as0];

    // B: rows {br, br+64, br+128 (v0 only)}, 16 shorts at (vt&7)*16
    const int br0 = tid >> 3, br1 = (tid + 256) >> 3;        // 0..31 / 32..63
    const int bs0 = (tid & 7) * 16;                          // shorts
    const unsigned short* bSrc0 = WtG + (size_t)br0 * H_ + bs0;
    const unsigned short* bSrc1 = WtG + (size_t)br1 * H_ + bs0;
    const int bswz0 = (br0 & 7) << 4, bswz1 = (br1 & 7) << 4;
    char* bDst0 = (char*)Bsm + br0 * 256;
    char* bDst1 = (char*)Bsm + br1 * 256;

    // compute-side fragment offsets (two row-tiles per wave)
    const int aOffA = (wm * 32 + lr) * BKP + q * 8;          // shorts
    const int aOffB = aOffA + 16 * BKP;
    int bOff[5];
#pragma unroll
    for (int tt = 0; tt < 5; ++tt) {
        const int row = wn * 80 + tt * 16 + lr;
        bOff[tt] = row * 256 + ((q * 16) ^ ((row & 7) << 4));   // bytes; ^(kk<<1)
    }

    floatx4 acc[5], acc2[5];
#pragma unroll
    for (int tt = 0; tt < 5; ++tt) {
        acc[tt]  = (floatx4){0.f, 0.f, 0.f, 0.f};
        acc2[tt] = (floatx4){0.f, 0.f, 0.f, 0.f};
    }

    // staging registers for one chunk (both virtual passes)
    float4 aR[8];
    u16x8  bR[10];

#define LOADREGS(k0) do {                                                      \
        _Pragma("unroll")                                                      \
        for (int i = 0; i < 4; ++i) {                                          \
            aR[i]     = *(const float4*)(aSrc0 + (k0) + i * 4);                \
            aR[4 + i] = *(const float4*)(aSrc1 + (k0) + i * 4);                \
        }                                                                      \
        bR[0] = *(const u16x8*)(bSrc0 + (k0));                                 \
        bR[1] = *(const u16x8*)(bSrc0 + (k0) + 8);                             \
        bR[2] = *(const u16x8*)(bSrc0 + (size_t)64 * H_ + (k0));               \
        bR[3] = *(const u16x8*)(bSrc0 + (size_t)64 * H_ + (k0) + 8);           \
        bR[4] = *(const u16x8*)(bSrc0 + (size_t)128 * H_ + (k0));              \
        bR[5] = *(const u16x8*)(bSrc0 + (size_t)128 * H_ + (k0) + 8);          \
        bR[6] = *(const u16x8*)(bSrc1 + (k0));                                 \
        bR[7] = *(const u16x8*)(bSrc1 + (k0) + 8);                             \
        bR[8] = *(const u16x8*)(bSrc1 + (size_t)64 * H_ + (k0));               \
        bR[9] = *(const u16x8*)(bSrc1 + (size_t)64 * H_ + (k0) + 8);           \
    } while (0)

#define WRITE_LDS() do {                                                       \
        *(u16x8*)(aDst0)     = cvt8u(aR[0], aR[1]);                            \
        *(u16x8*)(aDst0 + 8) = cvt8u(aR[2], aR[3]);                            \
        *(u16x8*)(aDst1)     = cvt8u(aR[4], aR[5]);                            \
        *(u16x8*)(aDst1 + 8) = cvt8u(aR[6], aR[7]);                            \
        *(u16x8*)(bDst0 + ((bs0 * 2)      ^ bswz0)) = bR[0];                   \
        *(u16x8*)(bDst0 + ((bs0 * 2 + 16) ^ bswz0)) = bR[1];                   \
        *(u16x8*)(bDst0 + 64 * 256 + ((bs0 * 2)      ^ bswz0)) = bR[2];        \
        *(u16x8*)(bDst0 + 64 * 256 + ((bs0 * 2 + 16) ^ bswz0)) = bR[3];        \
        *(u16x8*)(bDst0 + 128 * 256 + ((bs0 * 2)      ^ bswz0)) = bR[4];       \
        *(u16x8*)(bDst0 + 128 * 256 + ((bs0 * 2 + 16) ^ bswz0)) = bR[5];       \
        *(u16x8*)(bDst1 + ((bs0 * 2)      ^ bswz1)) = bR[6];                   \
        *(u16x8*)(bDst1 + ((bs0 * 2 + 16) ^ bswz1)) = bR[7];                   \
        *(u16x8*)(bDst1 + 64 * 256 + ((bs0 * 2)      ^ bswz1)) = bR[8];        \
        *(u16x8*)(bDst1 + 64 * 256 + ((bs0 * 2 + 16) ^ bswz1)) = bR[9];        \
    } while (0)

    LOADREGS(0);
    for (int t = 0; t < NCHUNK; ++t) {
        __syncthreads();                 // (a) prior chunk's LDS reads done
        WRITE_LDS();
        if (t < NCHUNK - 1) LOADREGS((t + 1) * BK);   // issue next loads now
        __syncthreads();                 // (b) LDS writes visible
        // compute chunk t: one B read feeds TWO row-tiles (10 MFMA / substep)
#pragma unroll
        for (int kk = 0; kk < BK; kk += 32) {
            short8 afr0 = *(const short8*)&Asm[aOffA + kk];
            short8 afr1 = *(const short8*)&Asm[aOffB + kk];
#pragma unroll
            for (int tt = 0; tt < 5; ++tt) {
                short8 bfr = *(const short8*)((const char*)Bsm + (bOff[tt] ^ (kk << 1)));
                acc[tt]  = __builtin_amdgcn_mfma_f32_16x16x32_bf16(afr0, bfr, acc[tt],  0, 0, 0);
                acc2[tt] = __builtin_amdgcn_mfma_f32_16x16x32_bf16(afr1, bfr, acc2[tt], 0, 0, 0);
            }
        }
    }
#undef LOADREGS
#undef WRITE_LDS

    // epilogue: logits -> BCE * mask -> sum (two row-tiles)
    float lsum = 0.0f;
#pragma unroll
    for (int tt = 0; tt < 5; ++tt) {
        const int col = wn * 80 + tt * 16 + lr;
        if (col < NVALID) {
            const float rb = rowBias[b * NPAD + col];
#pragma unroll
            for (int i = 0; i < 4; ++i) {
#pragma unroll
                for (int h = 0; h < 2; ++h) {
                    const int row = gm0 + wm * 32 + h * 16 + q * 4 + i;
                    const float l = (h ? acc2[tt][i] : acc[tt][i]) + rb;
                    float tgt;
                    if (col < 64)        tgt = oh[(size_t)row * R_ + col];
                    else if (col < 128)  tgt = ot[(size_t)row * R_ + (col - 64)];
                    else if (col == 128) tgt = ash[row];
                    else                 tgt = ast[row];
                    const float mk = masks[row];
                    const float bce = fmaxf(l, 0.0f) - l * tgt + log1pf(__expf(-fabsf(l)));
                    lsum += bce * mk;
                }
            }
        }
    }
    for (int o = 32; o > 0; o >>= 1) lsum += __shfl_down(lsum, o, 64);
    if (lane == 0) rbuf[wave] = lsum;
    __syncthreads();
    if (tid == 0) {
        atomicAdd(&accum[0], rbuf[0] + rbuf[1] + rbuf[2] + rbuf[3]);
        __threadfence();
        const unsigned int prev = atomicAdd((unsigned int*)(accum + 2), 1u);
        if (prev == gridDim.x - 1) {   // last block finalizes
            const float s = atomicAdd(&accum[0], 0.0f);
            const float m = atomicAdd(&accum[1], 0.0f);
            out[0] = s / m;
        }
    }
}

extern "C" void kernel_launch(void* const* d_in, const int* in_sizes, int n_in,
                              void* d_out, int out_size, void* d_ws, size_t ws_size,
                              hipStream_t stream) {
    const float* ctx   = (const float*)d_in[0];
    const float* masks = (const float*)d_in[1];
    const float* ash   = (const float*)d_in[2];
    const float* ast   = (const float*)d_in[3];
    const float* sh    = (const float*)d_in[4];
    const float* st    = (const float*)d_in[5];
    const float* oh    = (const float*)d_in[6];
    const float* ot    = (const float*)d_in[7];
    const float* Ws_h  = (const float*)d_in[8];
    const float* bs_h  = (const float*)d_in[9];
    const float* Ws_t  = (const float*)d_in[10];
    const float* bs_t  = (const float*)d_in[11];
    const float* Wo_h  = (const float*)d_in[12];
    const float* bo_h  = (const float*)d_in[13];
    const float* Wo_t  = (const float*)d_in[14];
    const float* bo_t  = (const float*)d_in[15];
    float* out = (float*)d_out;

    char* ws = (char*)d_ws;
    float* accum   = (float*)(ws + 0);                 // [0]=loss, [1]=msum, [2]=counter
    float* rowBias = (float*)(ws + 256);               // [32][160] fp32
    unsigned short* WtG = (unsigned short*)(ws + 256 + 32 * NPAD * 4); // [160][1024] bf16

    hipMemsetAsync(accum, 0, 12, stream);
    aux_kernel<<<TBLK + B_, 256, 0, stream>>>(ctx, sh, st, masks, Wo_h, Wo_t,
                                              Ws_h, Ws_t, bo_h, bo_t, bs_h, bs_t,
                                              WtG, rowBias, accum);
    main_kernel<<<M_ / MT, NTHR, 0, stream>>>(ctx, WtG, rowBias, masks,
                                              ash, ast, oh, ot, accum, out);
}